// Round 7
// baseline (150.151 us; speedup 1.0000x reference)
//
#include <hip/hip_runtime.h>

constexpr int Bn = 8, S = 2048, E = 1024, H = 64;
// E^-0.5 * log2(e) folded into q: scores come out of QK^T already in log2
// domain, so softmax is exp2f(s - m) with no per-element LOG2E multiply.
constexpr float SCALE = 0.03125f * 1.44269504f;

typedef __attribute__((ext_vector_type(8))) short short8;  // 8 bf16
typedef __attribute__((ext_vector_type(4))) float f32x4;   // MFMA C/D

__device__ __forceinline__ unsigned short f2bf(float f) {
  unsigned u = __builtin_bit_cast(unsigned, f);
  u += 0x7fffu + ((u >> 16) & 1u);    // RNE
  return (unsigned short)(u >> 16);
}
__device__ __forceinline__ ushort4 f4bf(float4 f) {
  return make_ushort4(f2bf(f.x), f2bf(f.y), f2bf(f.z), f2bf(f.w));
}

// ---------- W [1024][64] fp32 -> WT3 [3][64][1024] bf16 ----------
__global__ __launch_bounds__(256) void wtrans_kernel(
    const float* __restrict__ Wq, const float* __restrict__ Wk,
    const float* __restrict__ Wv, unsigned short* __restrict__ WT3) {
  __shared__ unsigned short tb[64][72];
  const int m = blockIdx.x >> 4;
  const int e0 = (blockIdx.x & 15) * 64;
  const float* W = (m == 0) ? Wq : (m == 1) ? Wk : Wv;
  const int t = threadIdx.x;
#pragma unroll
  for (int it = 0; it < 4; ++it) {
    int idx = t + it * 256;
    int r = idx >> 4, c4 = idx & 15;
    float4 f = ((const float4*)(W + (long)(e0 + r) * H))[c4];
    *(ushort4*)&tb[r][c4 * 4] = f4bf(f);
  }
  __syncthreads();
#pragma unroll
  for (int it = 0; it < 4; ++it) {
    int idx = t + it * 256;
    int h = idx >> 4, e4 = idx & 15;
    ushort4 u = make_ushort4(tb[e4 * 4 + 0][h], tb[e4 * 4 + 1][h],
                             tb[e4 * 4 + 2][h], tb[e4 * 4 + 3][h]);
    ((ushort4*)(WT3 + (long)(m * 64 + h) * E + e0))[e4] = u;
  }
}

// ---------- QKV GEMM, m97-style: M=32 x N=192, BK=128, LDS-dense ----------
__global__ __launch_bounds__(256) void qkv_kernel(
    const float* __restrict__ x, const unsigned short* __restrict__ WT3,
    unsigned short* __restrict__ q, unsigned short* __restrict__ kk,
    unsigned short* __restrict__ vT) {
  __shared__ unsigned short xs[32][136];    // [seq-row][e in chunk]
  __shared__ unsigned short ws[192][136];   // [out-col j][e in chunk]
  const int t = threadIdx.x;
  const int w = t >> 6, lane = t & 63, l15 = lane & 15, g = lane >> 4;
  const long row0 = (long)blockIdx.x * 32;
  const int xrow = t >> 5, xslot = t & 31;  // x: 8 rows x 32 float4 / iter
  const int wrow = t >> 4, wslot = t & 15;  // W: 16 rows x 16 short8 / iter

  f32x4 acc[2][3];
#pragma unroll
  for (int rt = 0; rt < 2; ++rt)
#pragma unroll
    for (int ct = 0; ct < 3; ++ct) acc[rt][ct] = f32x4{0.f, 0.f, 0.f, 0.f};

  float4 px[4];
  short8 pw[12];
  // prologue: chunk 0 -> regs -> LDS
#pragma unroll
  for (int it = 0; it < 4; ++it)
    px[it] = ((const float4*)(x + (row0 + xrow + it * 8) * E))[xslot];
#pragma unroll
  for (int it = 0; it < 12; ++it)
    pw[it] = *(const short8*)(WT3 + (long)(wrow + it * 16) * E + wslot * 8);
#pragma unroll
  for (int it = 0; it < 4; ++it)
    *(ushort4*)&xs[xrow + it * 8][xslot * 4] = f4bf(px[it]);
#pragma unroll
  for (int it = 0; it < 12; ++it)
    *(short8*)&ws[wrow + it * 16][wslot * 8] = pw[it];

  for (int c = 0; c < 8; ++c) {             // 8 chunks of 128 e
    __syncthreads();                        // staged chunk visible
    if (c < 7) {                            // dense prefetch of chunk c+1
      const int e0 = (c + 1) * 128;
#pragma unroll
      for (int it = 0; it < 4; ++it)
        px[it] = ((const float4*)(x + (row0 + xrow + it * 8) * E + e0))[xslot];
#pragma unroll
      for (int it = 0; it < 12; ++it)
        pw[it] = *(const short8*)(WT3 + (long)(wrow + it * 16) * E + e0 + wslot * 8);
    }
#pragma unroll
    for (int kh = 0; kh < 4; ++kh) {
      short8 a0 = *(const short8*)&xs[l15][kh * 32 + g * 8];
      short8 a1 = *(const short8*)&xs[16 + l15][kh * 32 + g * 8];
#pragma unroll
      for (int ct = 0; ct < 3; ++ct) {
        short8 b = *(const short8*)&ws[w * 48 + ct * 16 + l15][kh * 32 + g * 8];
        acc[0][ct] = __builtin_amdgcn_mfma_f32_16x16x32_bf16(a0, b, acc[0][ct], 0, 0, 0);
        acc[1][ct] = __builtin_amdgcn_mfma_f32_16x16x32_bf16(a1, b, acc[1][ct], 0, 0, 0);
      }
    }
    __syncthreads();                        // LDS reads done
    if (c < 7) {
#pragma unroll
      for (int it = 0; it < 4; ++it)
        *(ushort4*)&xs[xrow + it * 8][xslot * 4] = f4bf(px[it]);
#pragma unroll
      for (int it = 0; it < 12; ++it)
        *(short8*)&ws[wrow + it * 16][wslot * 8] = pw[it];
    }
  }

  const int bb = (int)(row0 >> 11);
  const int srow = (int)(row0 & 2047);
#pragma unroll
  for (int ct = 0; ct < 3; ++ct) {
    const int col = w * 48 + ct * 16 + l15;
    const int mm = col >> 6, ch = col & 63;
#pragma unroll
    for (int rt = 0; rt < 2; ++rt) {
      const int srl = rt * 16 + g * 4;
      if (mm == 0) {
#pragma unroll
        for (int r = 0; r < 4; ++r)
          q[(row0 + srl + r) * H + ch] = f2bf(acc[rt][ct][r] * SCALE);
      } else if (mm == 1) {
#pragma unroll
        for (int r = 0; r < 4; ++r)
          kk[(row0 + srl + r) * H + ch] = f2bf(acc[rt][ct][r]);
      } else {
        ushort4 v4 = make_ushort4(f2bf(acc[rt][ct][0]), f2bf(acc[rt][ct][1]),
                                  f2bf(acc[rt][ct][2]), f2bf(acc[rt][ct][3]));
        *(ushort4*)(vT + ((long)bb * H + ch) * S + srow + srl) = v4;
      }
    }
  }
}

// ---------- causal flash attention: block-cooperative LDS K/V (m214) -----
// 6 rounds of per-wave-private K/V loads all pinned attn at ~41us: per-CU
// time ~ passes/CU x full chain latency, overlap factor ~1 (66 x ~1500cyc
// = 41us matches). This port removes that invariant: block = 512thr/8waves
// owns 128 Q-rows (wave w: rows r0+16w, Q in regs); ALL waves consume the
// SAME K/V tile stream staged ONCE per block into LDS (VMEM requests /8).
// Staging: reg-staged (linear coalesced global read) -> XOR-swizzled LDS
// write (col16 ^= row&7; read side same XOR -> ds_read_b128 spreads 8
// 16B-slots over all 32 banks). Double-buffer, ONE barrier per tile:
//   issue loads(t+1) -> compute(buf) -> ds_write(buf^1) -> barrier
// (T14: global latency hides under compute; WAR on buf^1 is one barrier
// back). Causal: wave computes tile iff k0 <= its last row; element mask
// only on its diagonal tile. No cross-wave merge (waves own rows).
// Grid = 8b x 16 row-blocks = 128 blocks; wall = longest block (32 tiles).
__global__ __launch_bounds__(512) void attn_kernel(
    const unsigned short* __restrict__ q, const unsigned short* __restrict__ k,
    const unsigned short* __restrict__ vT, float* __restrict__ out) {
  __shared__ unsigned short Kl[2][64][64];  // swizzled [key][h],  8KB/buf
  __shared__ unsigned short Vl[2][64][64];  // swizzled [h][key],  8KB/buf
  __shared__ unsigned short pl[8][16][72];  // per-wave P^T [qrow][key]
  const int t = threadIdx.x;
  const int w = t >> 6, lane = t & 63, l15 = lane & 15, g = lane >> 4;
  const int b = blockIdx.x & 7, qb = blockIdx.x >> 3;   // qb in 0..15
  const int r0 = qb * 128;
  const int ntile = 2 * qb + 2;             // K64 tiles staged by the block
  const int myNt = 2 * qb + (w >> 2) + 1;   // tiles this wave computes
  const int qrow = r0 + w * 16 + l15;       // this lane's q-row (n index)
  const unsigned short* kb = k + (long)b * S * H;
  const unsigned short* vb = vT + (long)b * H * S;

  // staging geometry: thread t covers 16B slot (row = t>>3, col16 = t&7)
  const int srow = t >> 3, scol = t & 7;
  const int swz = (scol ^ (srow & 7)) * 8;  // swizzled col (shorts)

  short8 bq0, bq1;                          // Q B-frags: n=l15=qrow, k=h
  {
    const unsigned short* qp = q + ((long)b * S + qrow) * H + g * 8;
    bq0 = *(const short8*)qp;
    bq1 = *(const short8*)(qp + 32);
  }
  f32x4 O[4];
#pragma unroll
  for (int c = 0; c < 4; ++c) O[c] = f32x4{0.f, 0.f, 0.f, 0.f};
  float m_ = -1e30f, l_ = 0.f;              // l_ is per-lane partial

  const int rc0 = (g ^ (l15 & 7)) * 8;      // swizzled read cols (kh=0/1)
  const int rc1 = ((4 + g) ^ (l15 & 7)) * 8;

  // prologue: stage tile 0 into buf 0
  {
    uint4 pk = *(const uint4*)(kb + ((long)srow << 6) + scol * 8);
    uint4 pv = *(const uint4*)(vb + (long)srow * S + scol * 8);
    *(uint4*)&Kl[0][srow][swz] = pk;
    *(uint4*)&Vl[0][srow][swz] = pv;
    __syncthreads();
  }

  for (int kt = 0; kt < ntile; ++kt) {
    const int cur = kt & 1;
    const int k0 = kt * 64;
    const bool pf = (kt + 1 < ntile);
    uint4 pk, pv;
    if (pf) {                               // issue next-tile loads EARLY
      const int kn = k0 + 64;
      pk = *(const uint4*)(kb + ((long)(kn + srow) << 6) + scol * 8);
      pv = *(const uint4*)(vb + (long)srow * S + kn + scol * 8);
    }
    if (kt < myNt) {
      // ---- K frags from LDS (shared by all waves) ----
      short8 ak[4][2];
#pragma unroll
      for (int c = 0; c < 4; ++c) {
        ak[c][0] = *(const short8*)&Kl[cur][c * 16 + l15][rc0];
        ak[c][1] = *(const short8*)&Kl[cur][c * 16 + l15][rc1];
      }
      // ---- S^T = K Q^T : D[m=key][n=qrow], log2 units ----
      f32x4 sc[4];
#pragma unroll
      for (int c = 0; c < 4; ++c) {
        sc[c] = f32x4{0.f, 0.f, 0.f, 0.f};
        sc[c] = __builtin_amdgcn_mfma_f32_16x16x32_bf16(ak[c][0], bq0, sc[c], 0, 0, 0);
        sc[c] = __builtin_amdgcn_mfma_f32_16x16x32_bf16(ak[c][1], bq1, sc[c], 0, 0, 0);
      }
      if (kt == myNt - 1) {                 // diagonal tile: mask key > qrow
#pragma unroll
        for (int c = 0; c < 4; ++c)
#pragma unroll
          for (int r = 0; r < 4; ++r)
            if (k0 + c * 16 + g * 4 + r > qrow) sc[c][r] = -1e30f;
      }
      // ---- per-lane tree max ----
      float x0 = fmaxf(fmaxf(sc[0][0], sc[0][1]), fmaxf(sc[0][2], sc[0][3]));
      float x1 = fmaxf(fmaxf(sc[1][0], sc[1][1]), fmaxf(sc[1][2], sc[1][3]));
      float x2 = fmaxf(fmaxf(sc[2][0], sc[2][1]), fmaxf(sc[2][2], sc[2][3]));
      float x3 = fmaxf(fmaxf(sc[3][0], sc[3][1]), fmaxf(sc[3][2], sc[3][3]));
      float pmax = fmaxf(fmaxf(x0, x1), fmaxf(x2, x3));
      // ---- defer-max (T13): slow path only on >THR growth ----
      if (!__all(pmax - m_ <= 10.0f)) {
        float mx = fmaxf(pmax, __shfl_xor(pmax, 16));
        mx = fmaxf(mx, __shfl_xor(mx, 32));
        float mn = fmaxf(m_, mx);           // uniform across the 4 g-groups
        float al = exp2f(m_ - mn);
        l_ *= al;
#pragma unroll
        for (int c = 0; c < 4; ++c)
#pragma unroll
          for (int r = 0; r < 4; ++r) O[c][r] *= al;
        m_ = mn;
      }
#pragma unroll
      for (int c = 0; c < 4; ++c)
#pragma unroll
        for (int r = 0; r < 4; ++r) sc[c][r] = exp2f(sc[c][r] - m_);
      float s0 = (sc[0][0] + sc[0][1]) + (sc[0][2] + sc[0][3]);
      float s1 = (sc[1][0] + sc[1][1]) + (sc[1][2] + sc[1][3]);
      float s2 = (sc[2][0] + sc[2][1]) + (sc[2][2] + sc[2][3]);
      float s3 = (sc[3][0] + sc[3][1]) + (sc[3][2] + sc[3][3]);
      l_ += (s0 + s1) + (s2 + s3);          // per-lane partial; no shuffles
      // ---- P^T -> per-wave LDS ----
#pragma unroll
      for (int c = 0; c < 4; ++c) {
        ushort4 p4 = make_ushort4(f2bf(sc[c][0]), f2bf(sc[c][1]),
                                  f2bf(sc[c][2]), f2bf(sc[c][3]));
        *(ushort4*)&pl[w][l15][c * 16 + g * 4] = p4;
      }
      // ---- O^T += V^T P^T, V frags from LDS ----
      short8 bp0 = *(const short8*)&pl[w][l15][g * 8];
      short8 bp1 = *(const short8*)&pl[w][l15][32 + g * 8];
#pragma unroll
      for (int c = 0; c < 4; ++c) {
        short8 av0 = *(const short8*)&Vl[cur][c * 16 + l15][rc0];
        short8 av1 = *(const short8*)&Vl[cur][c * 16 + l15][rc1];
        O[c] = __builtin_amdgcn_mfma_f32_16x16x32_bf16(av0, bp0, O[c], 0, 0, 0);
        O[c] = __builtin_amdgcn_mfma_f32_16x16x32_bf16(av1, bp1, O[c], 0, 0, 0);
      }
    }
    if (pf) {                               // write next tile LATE (T14)
      *(uint4*)&Kl[cur ^ 1][srow][swz] = pk;
      *(uint4*)&Vl[cur ^ 1][srow][swz] = pv;
    }
    __syncthreads();                        // staged visible; buf reads done
  }

  // complete the deferred l reduction (sum partials across the 4 g-groups)
  l_ += __shfl_xor(l_, 16);
  l_ += __shfl_xor(l_, 32);
  const float inv = 1.0f / l_;
  float* op = out + ((long)b * S + qrow) * H + g * 4;
#pragma unroll
  for (int c = 0; c < 4; ++c)
    *(float4*)(op + c * 16) = make_float4(O[c][0] * inv, O[c][1] * inv,
                                          O[c][2] * inv, O[c][3] * inv);
}

extern "C" void kernel_launch(void* const* d_in, const int* in_sizes, int n_in,
                              void* d_out, int out_size, void* d_ws, size_t ws_size,
                              hipStream_t stream) {
  const float* x  = (const float*)d_in[0];
  const float* Wq = (const float*)d_in[1];
  const float* Wk = (const float*)d_in[2];
  const float* Wv = (const float*)d_in[3];
  float* outp = (float*)d_out;
  unsigned short* WT3 = (unsigned short*)d_ws;                       // 384 KB
  unsigned short* q  = (unsigned short*)((char*)d_ws + 512 * 1024);  // 2 MB each
  unsigned short* kk = q + (size_t)Bn * S * H;
  unsigned short* vT = kk + (size_t)Bn * S * H;
  wtrans_kernel<<<dim3(48), dim3(256), 0, stream>>>(Wq, Wk, Wv, WT3);
  qkv_kernel<<<dim3((Bn * S) / 32), dim3(256), 0, stream>>>(x, WT3, q, kk, vT);
  attn_kernel<<<dim3(Bn * 16), dim3(512), 0, stream>>>(q, kk, vT, outp);
}